// Round 1
// 730.522 us; speedup vs baseline: 1.0554x; 1.0554x over previous
//
#include <hip/hip_runtime.h>

typedef unsigned short u16;
typedef __bf16 bf16x8 __attribute__((ext_vector_type(8)));
typedef float f32x4 __attribute__((ext_vector_type(4)));

#define BS_TOT 32768   // B*S
#define SS 4096
#define DD 1024
#define MM 32

__device__ __forceinline__ float bf2f(u16 u) {
    union { float f; unsigned int i; } c; c.i = ((unsigned int)u) << 16; return c.f;
}
__device__ __forceinline__ u16 f2bf(float f) {
    union { float f; unsigned int i; } c; c.f = f;
    unsigned int r = c.i + 0x7FFFu + ((c.i >> 16) & 1u);
    return (u16)(r >> 16);
}
__device__ __forceinline__ f32x4 mfma16(bf16x8 a, bf16x8 b, f32x4 c) {
    return __builtin_amdgcn_mfma_f32_16x16x32_bf16(a, b, c, 0, 0, 0);
}
__device__ __forceinline__ u16 cvt_in(const void* p, size_t i, int f32m) {
    return f32m ? f2bf(((const float*)p)[i]) : ((const u16*)p)[i];
}
__device__ __forceinline__ uint4 pack8(float4 a, float4 b) {
    uint4 v;
    v.x = (unsigned)f2bf(a.x) | ((unsigned)f2bf(a.y) << 16);
    v.y = (unsigned)f2bf(a.z) | ((unsigned)f2bf(a.w) << 16);
    v.z = (unsigned)f2bf(b.x) | ((unsigned)f2bf(b.y) << 16);
    v.w = (unsigned)f2bf(b.z) | ((unsigned)f2bf(b.w) << 16);
    return v;
}
// async global->LDS, 16B per lane. LDS dest is wave-uniform base + lane*16.
__device__ __forceinline__ void gload16(u16* l, const u16* g) {
    __builtin_amdgcn_global_load_lds(
        (const __attribute__((address_space(1))) unsigned int*)(g),
        (__attribute__((address_space(3))) unsigned int*)(l),
        16, 0, 0);
}

// ---------------------------------------------------------------------------
// K-1: dtype detector (insurance; evidence says inputs are f32). flag=1 -> f32.
// ---------------------------------------------------------------------------
__global__ __launch_bounds__(64) void zej_detect(const unsigned int* __restrict__ xw,
                                                 int* __restrict__ flag)
{
    int lane = threadIdx.x;
    int cnt = 0;
#pragma unroll
    for (int i = 0; i < 16; i++) {
        unsigned int w = xw[lane * 16 + i];
        unsigned int e = (w >> 7) & 0xFFu;
        cnt += (e >= 110u && e <= 135u) ? 1 : 0;
    }
#pragma unroll
    for (int off = 32; off > 0; off >>= 1) cnt += __shfl_down(cnt, off);
    if (lane == 0) *flag = (cnt < 512) ? 1 : 0;
}

// ---------------------------------------------------------------------------
// K0: pack weights/biases into bf16 n-major layouts.
//   W3T[96][1024] = [Wr|Ww|Wm]^T,  WoxT[1024][1024] = Wo[:1024]^T (x-half)
//   biasp[0:96] = br|bw|bm
// ---------------------------------------------------------------------------
__global__ __launch_bounds__(256) void zej_pack(
    const void* __restrict__ Wr, const void* __restrict__ Ww, const void* __restrict__ Wm,
    const void* __restrict__ Wo,
    const void* __restrict__ br, const void* __restrict__ bw, const void* __restrict__ bm,
    u16* __restrict__ W3T, u16* __restrict__ WoxT, u16* __restrict__ biasp,
    const int* __restrict__ flag)
{
    const int f32m = *flag;
    int i = blockIdx.x * 256 + threadIdx.x;
    if (i < 98304) {            // W3T
        int j = i >> 10, k = i & 1023;
        W3T[i] = (j < 32) ? cvt_in(Wr, (size_t)k * 32 + j, f32m)
               : (j < 64) ? cvt_in(Ww, (size_t)k * 32 + (j - 32), f32m)
                          : cvt_in(Wm, (size_t)k * 32 + (j - 64), f32m);
        return;
    }
    i -= 98304;
    if (i < 1048576) {          // WoxT: [n][k] = Wo[k][n], k < 1024
        int n = i >> 10, k = i & 1023;
        WoxT[i] = cvt_in(Wo, (size_t)k * 1024 + n, f32m);
        return;
    }
    i -= 1048576;
    if (i < 96) {
        biasp[i] = (i < 32) ? cvt_in(br, i, f32m)
                 : (i < 64) ? cvt_in(bw, i - 32, f32m)
                            : cvt_in(bm, i - 64, f32m);
    }
}

// ---------------------------------------------------------------------------
// K0b: Wpm = Wp @ Wo_m  (32x1024 @ 1024x1024, f32 accum) -> WpmT[n][32] bf16
//      bpm[n] = bo[n] + sum_d bp[d]*Wo_m[d][n]  (f32)
// Grid 16 x 256: thread (n = bx*64 + t&63, m-group g = t>>6 owns 8 m's).
// Wp chunk staged transposed in LDS -> inner reads are wave-broadcast.
// ---------------------------------------------------------------------------
__global__ __launch_bounds__(256) void zej_wpm(
    const void* __restrict__ Wp, const void* __restrict__ Wo,
    const void* __restrict__ bp, const void* __restrict__ bo,
    u16* __restrict__ WpmT, float* __restrict__ bpm, const int* __restrict__ flag)
{
    __shared__ float wpc[128 * 32];   // [dd][m], 16 KB
    __shared__ float bpc[128];
    const int f32m = *flag;
    const int t = threadIdx.x;
    const int n = blockIdx.x * 64 + (t & 63);
    const int g = t >> 6;            // 0..3

    float acc[8];
#pragma unroll
    for (int j = 0; j < 8; j++) acc[j] = 0.f;
    float bacc = 0.f;

    for (int d0 = 0; d0 < 1024; d0 += 128) {
        __syncthreads();
        for (int i = t; i < 4096; i += 256) {        // coalesced Wp read, transposed store
            int m = i >> 7, dd = i & 127;
            float v = f32m ? ((const float*)Wp)[m * 1024 + d0 + dd]
                           : bf2f(((const u16*)Wp)[m * 1024 + d0 + dd]);
            wpc[dd * 32 + m] = v;
        }
        if (t < 128)
            bpc[t] = f32m ? ((const float*)bp)[d0 + t] : bf2f(((const u16*)bp)[d0 + t]);
        __syncthreads();
        for (int dd = 0; dd < 128; dd++) {
            int d = d0 + dd;
            float w = f32m ? ((const float*)Wo)[(size_t)(1024 + d) * 1024 + n]
                           : bf2f(((const u16*)Wo)[(size_t)(1024 + d) * 1024 + n]);
            const float* wp8 = &wpc[dd * 32 + g * 8];   // wave-broadcast
#pragma unroll
            for (int j = 0; j < 8; j++) acc[j] += wp8[j] * w;
            if (g == 0) bacc += bpc[dd] * w;
        }
    }
#pragma unroll
    for (int j = 0; j < 8; j++) WpmT[(size_t)n * 32 + g * 8 + j] = f2bf(acc[j]);
    if (g == 0) {
        float b = f32m ? ((const float*)bo)[n] : bf2f(((const u16*)bo)[n]);
        bpm[n] = bacc + b;
    }
}

// ---------------------------------------------------------------------------
// K1: gates = x @ [Wr|Ww|Wm] (+bias, sigmoid on cols<64). Also emits xb (bf16 x),
// since every x element is staged here exactly once anyway.
// ---------------------------------------------------------------------------
__global__ __launch_bounds__(256) void zej_gates(
    const void* __restrict__ x, const u16* __restrict__ W3T,
    const u16* __restrict__ biasp, u16* __restrict__ gates,
    u16* __restrict__ xb, const int* __restrict__ flag)
{
    __shared__ __align__(16) u16 As[128][88];
    __shared__ __align__(16) u16 Bs[96][88];
    const int f32m = *flag;
    const int t = threadIdx.x;
    const int lane = t & 63;
    const int wv = t >> 6;
    const int row0 = blockIdx.x * 128;
    const int lm = lane & 15, lq = lane >> 4;

    f32x4 acc[2][6];
    f32x4 z = {0.f, 0.f, 0.f, 0.f};
#pragma unroll
    for (int i = 0; i < 2; i++)
#pragma unroll
        for (int j = 0; j < 6; j++) acc[i][j] = z;

    for (int k0 = 0; k0 < 1024; k0 += 64) {
#pragma unroll
        for (int c = 0; c < 4; c++) {            // A: 128x64
            int chunk = t + c * 256;
            int r = chunk >> 3, kc = (chunk & 7) * 8;
            size_t gi = (size_t)(row0 + r) * 1024 + k0 + kc;
            uint4 v;
            if (f32m) {
                const float* xf = (const float*)x;
                float4 f0 = *(const float4*)(xf + gi);
                float4 f1 = *(const float4*)(xf + gi + 4);
                v = pack8(f0, f1);
            } else {
                v = *(const uint4*)((const u16*)x + gi);
            }
            *(uint4*)&As[r][kc] = v;
            *(uint4*)(xb + gi) = v;              // bf16 x for zej_out
        }
#pragma unroll
        for (int c = 0; c < 3; c++) {            // B: 96x64
            int chunk = t + c * 256;
            int j = chunk >> 3, kc = (chunk & 7) * 8;
            *(uint4*)&Bs[j][kc] = *(const uint4*)&W3T[j * 1024 + k0 + kc];
        }
        __syncthreads();
#pragma unroll
        for (int ks = 0; ks < 2; ks++) {
            int kk = ks * 32 + lq * 8;
            bf16x8 a[2], b[6];
#pragma unroll
            for (int rt = 0; rt < 2; rt++) a[rt] = *(const bf16x8*)&As[wv * 32 + rt * 16 + lm][kk];
#pragma unroll
            for (int ct = 0; ct < 6; ct++) b[ct] = *(const bf16x8*)&Bs[ct * 16 + lm][kk];
#pragma unroll
            for (int rt = 0; rt < 2; rt++)
#pragma unroll
                for (int ct = 0; ct < 6; ct++)
                    acc[rt][ct] = mfma16(a[rt], b[ct], acc[rt][ct]);
        }
        __syncthreads();
    }
#pragma unroll
    for (int rt = 0; rt < 2; rt++) {
#pragma unroll
        for (int ct = 0; ct < 6; ct++) {
            int col = ct * 16 + lm;
            float bias = bf2f(biasp[col]);
            bool sig = (col < 64);
#pragma unroll
            for (int p = 0; p < 4; p++) {
                int R = row0 + wv * 32 + rt * 16 + lq * 4 + p;
                float v = acc[rt][ct][p] + bias;
                if (sig) v = 1.f / (1.f + __expf(-v));
                gates[R * 96 + col] = f2bf(v);
            }
        }
    }
}

// ---------------------------------------------------------------------------
// K2: per-channel linear-recurrence scan.  One wave per (b,m) channel.
// ---------------------------------------------------------------------------
__global__ __launch_bounds__(64) void zej_scan(
    const u16* __restrict__ gates, u16* __restrict__ rm)
{
    const int c = blockIdx.x;       // 0..255
    const int b = c >> 5;
    const int m = c & 31;
    const int lane = threadIdx.x;
    const u16* gb = gates + (size_t)b * SS * 96;
    const int tbase = lane * 64;

    float A = 1.f, Bc = 0.f;
    for (int i = 0; i < 64; i++) {
        int idx = (tbase + i) * 96;
        float w = bf2f(gb[idx + 32 + m]);
        float nm = bf2f(gb[idx + 64 + m]);
        float a = 1.f - w;
        Bc = a * Bc + w * nm;
        A *= a;
    }
    for (int off = 1; off < 64; off <<= 1) {
        float Ap = __shfl_up(A, off);
        float Bp = __shfl_up(Bc, off);
        if (lane >= off) { Bc = A * Bp + Bc; A = A * Ap; }
    }
    float Bprev = __shfl_up(Bc, 1);
    float mem = (lane == 0) ? 0.f : Bprev;

    for (int i = 0; i < 64; i++) {
        int idx = (tbase + i) * 96;
        float r = bf2f(gb[idx + m]);
        float w = bf2f(gb[idx + 32 + m]);
        float nm = bf2f(gb[idx + 64 + m]);
        rm[((size_t)b * SS + tbase + i) * 32 + m] = f2bf(r * mem);
        mem = (1.f - w) * mem + w * nm;
    }
}

// ---------------------------------------------------------------------------
// K4: out = tanh(xb @ Wo_x (K=1024) + rm @ Wpm (K=32) + bpm).  f32 OUTPUT.
// m97-style: global_load_lds width=16 into linear [128][64] LDS, with
// pre-swizzled global source + XOR-swizzled ds_read (byte ^= (row&7)<<4)
// so fragment reads spread across all 32 banks.
// ---------------------------------------------------------------------------
__global__ __launch_bounds__(256) void zej_out(
    const u16* __restrict__ xb, const u16* __restrict__ rm,
    const u16* __restrict__ WoxT, const u16* __restrict__ WpmT,
    const float* __restrict__ bpm, float* __restrict__ out)
{
    __shared__ __align__(16) u16 As[128 * 64];   // 16 KB, linear, swizzled content
    __shared__ __align__(16) u16 Bs[128 * 64];
    const int t = threadIdx.x;
    const int lane = t & 63;
    const int wv = t >> 6;
    const int wr = (wv >> 1) * 64;
    const int wc = (wv & 1) * 64;
    const int row0 = blockIdx.x * 128;
    const int n0 = blockIdx.y * 128;
    const int lm = lane & 15, lq = lane >> 4;

    f32x4 acc[4][4];
    f32x4 z = {0.f, 0.f, 0.f, 0.f};
#pragma unroll
    for (int i = 0; i < 4; i++)
#pragma unroll
        for (int j = 0; j < 4; j++) acc[i][j] = z;

    // staging geometry: one gload16 = 64 lanes * 16B = 8 rows of 128B.
    const int sr = lane >> 3;              // row within 8-row stripe
    const int slot = lane & 7;             // 16B slot within row
    const int kcs = 8 * (slot ^ sr);       // pre-swizzled source column (elems)

    for (int k0 = 0; k0 < 1024; k0 += 64) {
#pragma unroll
        for (int i = 0; i < 4; i++) {
            int ra = (wv * 4 + i) * 8 + sr;
            gload16(&As[(wv * 4 + i) * 512], xb   + (size_t)(row0 + ra) * 1024 + k0 + kcs);
            gload16(&Bs[(wv * 4 + i) * 512], WoxT + (size_t)(n0  + ra) * 1024 + k0 + kcs);
        }
        __syncthreads();                   // compiler drains vmcnt(0) here
#pragma unroll
        for (int ks = 0; ks < 2; ks++) {
            bf16x8 a[4], b[4];
#pragma unroll
            for (int rt = 0; rt < 4; rt++) {
                int R = wr + rt * 16 + lm;
                int cb = (ks * 64 + lq * 16) ^ ((R & 7) << 4);
                a[rt] = *(const bf16x8*)((const char*)As + R * 128 + cb);
            }
#pragma unroll
            for (int ct = 0; ct < 4; ct++) {
                int R = wc + ct * 16 + lm;
                int cb = (ks * 64 + lq * 16) ^ ((R & 7) << 4);
                b[ct] = *(const bf16x8*)((const char*)Bs + R * 128 + cb);
            }
#pragma unroll
            for (int rt = 0; rt < 4; rt++)
#pragma unroll
                for (int ct = 0; ct < 4; ct++)
                    acc[rt][ct] = mfma16(a[rt], b[ct], acc[rt][ct]);
        }
        __syncthreads();
    }

    // K=32 tail: rm @ WpmT. Tile rows are 64B (4 slots); swizzle within 4.
    {
        const int sr2 = lane >> 2;         // 0..15
        const int slot2 = lane & 3;
        const int kcs2 = 8 * (slot2 ^ (sr2 & 3));
#pragma unroll
        for (int i = 0; i < 2; i++) {
            int ra = (wv * 2 + i) * 16 + sr2;
            gload16(&As[(wv * 2 + i) * 512], rm   + (size_t)(row0 + ra) * 32 + kcs2);
            gload16(&Bs[(wv * 2 + i) * 512], WpmT + (size_t)(n0  + ra) * 32 + kcs2);
        }
        __syncthreads();
        bf16x8 a[4], b[4];
#pragma unroll
        for (int rt = 0; rt < 4; rt++) {
            int R = wr + rt * 16 + lm;
            a[rt] = *(const bf16x8*)((const char*)As + R * 64 + ((lq * 16) ^ ((R & 3) << 4)));
        }
#pragma unroll
        for (int ct = 0; ct < 4; ct++) {
            int R = wc + ct * 16 + lm;
            b[ct] = *(const bf16x8*)((const char*)Bs + R * 64 + ((lq * 16) ^ ((R & 3) << 4)));
        }
#pragma unroll
        for (int rt = 0; rt < 4; rt++)
#pragma unroll
            for (int ct = 0; ct < 4; ct++)
                acc[rt][ct] = mfma16(a[rt], b[ct], acc[rt][ct]);
    }

#pragma unroll
    for (int rt = 0; rt < 4; rt++) {
#pragma unroll
        for (int ct = 0; ct < 4; ct++) {
            int n = n0 + wc + ct * 16 + lm;
            float bias = bpm[n];
#pragma unroll
            for (int p = 0; p < 4; p++) {
                int R = row0 + wr + rt * 16 + lq * 4 + p;
                float v = acc[rt][ct][p] + bias;
                float e = __expf(2.f * v);          // tanh(v) = 1 - 2/(e^{2v}+1)
                out[(size_t)R * 1024 + n] = 1.f - 2.f / (e + 1.f);
            }
        }
    }
}

// ---------------------------------------------------------------------------
extern "C" void kernel_launch(void* const* d_in, const int* in_sizes, int n_in,
                              void* d_out, int out_size, void* d_ws, size_t ws_size,
                              hipStream_t stream)
{
    const void* x  = d_in[0];
    const void* Wr = d_in[1];
    const void* br = d_in[2];
    const void* Ww = d_in[3];
    const void* bw = d_in[4];
    const void* Wm = d_in[5];
    const void* bm = d_in[6];
    const void* Wp = d_in[7];
    const void* bp = d_in[8];
    const void* Wo = d_in[9];
    const void* bo = d_in[10];
    float* out = (float*)d_out;

    char* ws = (char*)d_ws;
    int* flag   = (int*)ws;                    // 4 B (pad 1 KiB)
    u16* W3T    = (u16*)(ws + 1024);           //  96*1024*2   = 196608   -> 197632
    u16* WoxT   = (u16*)(ws + 197632);         //  1024*1024*2 = 2097152  -> 2294784
    u16* WpmT   = (u16*)(ws + 2294784);        //  1024*32*2   = 65536    -> 2360320
    u16* biasp  = (u16*)(ws + 2360320);        //  96*2 -> pad 1024       -> 2361344
    float* bpm  = (float*)(ws + 2361344);      //  1024*4      = 4096     -> 2365440
    u16* gates  = (u16*)(ws + 2365440);        //  32768*96*2  = 6291456  -> 8656896
    u16* rm     = (u16*)(ws + 8656896);        //  32768*32*2  = 2097152  -> 10754048
    u16* xb     = (u16*)(ws + 10754048);       //  32768*1024*2= 67108864 -> 77862912

    zej_detect<<<1, 64, 0, stream>>>((const unsigned int*)x, flag);
    zej_pack<<<4481, 256, 0, stream>>>(Wr, Ww, Wm, Wo, br, bw, bm,
                                       W3T, WoxT, biasp, flag);
    zej_wpm<<<16, 256, 0, stream>>>(Wp, Wo, bp, bo, WpmT, bpm, flag);
    zej_gates<<<BS_TOT / 128, 256, 0, stream>>>(x, W3T, biasp, gates, xb, flag);
    zej_scan<<<256, 64, 0, stream>>>(gates, rm);
    zej_out<<<dim3(BS_TOT / 128, 8), 256, 0, stream>>>(xb, rm, WoxT, WpmT, bpm, out);
}

// Round 2
// 450.209 us; speedup vs baseline: 1.7126x; 1.6226x over previous
//
#include <hip/hip_runtime.h>

typedef unsigned short u16;
typedef __bf16 bf16x8 __attribute__((ext_vector_type(8)));
typedef float f32x4 __attribute__((ext_vector_type(4)));

#define BS_TOT 32768   // B*S
#define SS 4096
#define DD 1024
#define MM 32

__device__ __forceinline__ float bf2f(u16 u) {
    union { float f; unsigned int i; } c; c.i = ((unsigned int)u) << 16; return c.f;
}
__device__ __forceinline__ u16 f2bf(float f) {
    union { float f; unsigned int i; } c; c.f = f;
    unsigned int r = c.i + 0x7FFFu + ((c.i >> 16) & 1u);
    return (u16)(r >> 16);
}
__device__ __forceinline__ f32x4 mfma16(bf16x8 a, bf16x8 b, f32x4 c) {
    return __builtin_amdgcn_mfma_f32_16x16x32_bf16(a, b, c, 0, 0, 0);
}
__device__ __forceinline__ u16 cvt_in(const void* p, size_t i, int f32m) {
    return f32m ? f2bf(((const float*)p)[i]) : ((const u16*)p)[i];
}
__device__ __forceinline__ uint4 pack8(float4 a, float4 b) {
    uint4 v;
    v.x = (unsigned)f2bf(a.x) | ((unsigned)f2bf(a.y) << 16);
    v.y = (unsigned)f2bf(a.z) | ((unsigned)f2bf(a.w) << 16);
    v.z = (unsigned)f2bf(b.x) | ((unsigned)f2bf(b.y) << 16);
    v.w = (unsigned)f2bf(b.z) | ((unsigned)f2bf(b.w) << 16);
    return v;
}
// async global->LDS, 16B per lane. LDS dest is wave-uniform base + lane*16.
__device__ __forceinline__ void gload16(u16* l, const u16* g) {
    __builtin_amdgcn_global_load_lds(
        (const __attribute__((address_space(1))) unsigned int*)(g),
        (__attribute__((address_space(3))) unsigned int*)(l),
        16, 0, 0);
}

// ---------------------------------------------------------------------------
// K-1: dtype detector (insurance; evidence says inputs are f32). flag=1 -> f32.
// ---------------------------------------------------------------------------
__global__ __launch_bounds__(64) void zej_detect(const unsigned int* __restrict__ xw,
                                                 int* __restrict__ flag)
{
    int lane = threadIdx.x;
    int cnt = 0;
#pragma unroll
    for (int i = 0; i < 16; i++) {
        unsigned int w = xw[lane * 16 + i];
        unsigned int e = (w >> 7) & 0xFFu;
        cnt += (e >= 110u && e <= 135u) ? 1 : 0;
    }
#pragma unroll
    for (int off = 32; off > 0; off >>= 1) cnt += __shfl_down(cnt, off);
    if (lane == 0) *flag = (cnt < 512) ? 1 : 0;
}

// ---------------------------------------------------------------------------
// K0: pack weights/biases into bf16 n-major layouts.
//   W3T[96][1024] = [Wr|Ww|Wm]^T,  WoxT[1024][1024] = Wo[:1024]^T (x-half)
//   biasp[0:96] = br|bw|bm
// ---------------------------------------------------------------------------
__global__ __launch_bounds__(256) void zej_pack(
    const void* __restrict__ Wr, const void* __restrict__ Ww, const void* __restrict__ Wm,
    const void* __restrict__ Wo,
    const void* __restrict__ br, const void* __restrict__ bw, const void* __restrict__ bm,
    u16* __restrict__ W3T, u16* __restrict__ WoxT, u16* __restrict__ biasp,
    const int* __restrict__ flag)
{
    const int f32m = *flag;
    int i = blockIdx.x * 256 + threadIdx.x;
    if (i < 98304) {            // W3T
        int j = i >> 10, k = i & 1023;
        W3T[i] = (j < 32) ? cvt_in(Wr, (size_t)k * 32 + j, f32m)
               : (j < 64) ? cvt_in(Ww, (size_t)k * 32 + (j - 32), f32m)
                          : cvt_in(Wm, (size_t)k * 32 + (j - 64), f32m);
        return;
    }
    i -= 98304;
    if (i < 1048576) {          // WoxT: [n][k] = Wo[k][n], k < 1024
        int n = i >> 10, k = i & 1023;
        WoxT[i] = cvt_in(Wo, (size_t)k * 1024 + n, f32m);
        return;
    }
    i -= 1048576;
    if (i < 96) {
        biasp[i] = (i < 32) ? cvt_in(br, i, f32m)
                 : (i < 64) ? cvt_in(bw, i - 32, f32m)
                            : cvt_in(bm, i - 64, f32m);
    }
}

// ---------------------------------------------------------------------------
// K0b-A: partial Wpm.  Grid 256 = (nb 0..15) x (kb 0..15).
// Block (nb,kb): part[kb][m][nb*64+n] = sum_{dd<64} Wp[m][kb*64+dd]*Wo_m[kb*64+dd][n]
// plus bp row at m=32.  part layout: [16][33][1024] f32 (aliases gates buffer;
// zej_gates only writes it after zej_wpm_b in stream order).
// ---------------------------------------------------------------------------
__global__ __launch_bounds__(256) void zej_wpm_a(
    const void* __restrict__ Wp, const void* __restrict__ Wo,
    const void* __restrict__ bp,
    float* __restrict__ part, const int* __restrict__ flag)
{
    __shared__ float wpc[64 * 33];   // [dd][m], stride 33 -> conflict-free
    __shared__ float bpc[64];
    const int f32m = *flag;
    const int t = threadIdx.x;
    const int nb = blockIdx.x & 15;
    const int kb = blockIdx.x >> 4;
    const int d0 = kb * 64;

    for (int i = t; i < 2048; i += 256) {     // Wp chunk, coalesced over dd
        int m = i >> 6, dd = i & 63;
        float v = f32m ? ((const float*)Wp)[m * 1024 + d0 + dd]
                       : bf2f(((const u16*)Wp)[m * 1024 + d0 + dd]);
        wpc[dd * 33 + m] = v;
    }
    if (t < 64)
        bpc[t] = f32m ? ((const float*)bp)[d0 + t] : bf2f(((const u16*)bp)[d0 + t]);
    __syncthreads();

    const int n = nb * 64 + (t & 63);
    const int g = t >> 6;                     // 0..3, owns m = g*8..g*8+7
    float acc[8];
#pragma unroll
    for (int j = 0; j < 8; j++) acc[j] = 0.f;
    float bacc = 0.f;

    for (int dd = 0; dd < 64; dd++) {
        float w = f32m ? ((const float*)Wo)[(size_t)(1024 + d0 + dd) * 1024 + n]
                       : bf2f(((const u16*)Wo)[(size_t)(1024 + d0 + dd) * 1024 + n]);
        const float* wp8 = &wpc[dd * 33 + g * 8];   // wave-broadcast
#pragma unroll
        for (int j = 0; j < 8; j++) acc[j] += wp8[j] * w;
        if (g == 0) bacc += bpc[dd] * w;
    }
    float* pk = part + (size_t)kb * 33792;    // 33*1024
#pragma unroll
    for (int j = 0; j < 8; j++) pk[(g * 8 + j) * 1024 + n] = acc[j];
    if (g == 0) pk[32 * 1024 + n] = bacc;
}

// ---------------------------------------------------------------------------
// K0b-B: reduce 16 partials -> WpmT[n][32] bf16, bpm[n] f32 (+bo).
// Grid 132: blocks [0,128) -> WpmT (m = bid>>2, n = (bid&3)*256+t);
//           blocks [128,132) -> bpm.
// ---------------------------------------------------------------------------
__global__ __launch_bounds__(256) void zej_wpm_b(
    const float* __restrict__ part, const void* __restrict__ bo,
    u16* __restrict__ WpmT, float* __restrict__ bpm, const int* __restrict__ flag)
{
    const int f32m = *flag;
    const int t = threadIdx.x;
    const int bid = blockIdx.x;
    if (bid < 128) {
        int m = bid >> 2;
        int n = (bid & 3) * 256 + t;
        float acc = 0.f;
#pragma unroll
        for (int kb = 0; kb < 16; kb++) acc += part[(size_t)kb * 33792 + m * 1024 + n];
        WpmT[(size_t)n * 32 + m] = f2bf(acc);
    } else {
        int n = (bid - 128) * 256 + t;
        float acc = 0.f;
#pragma unroll
        for (int kb = 0; kb < 16; kb++) acc += part[(size_t)kb * 33792 + 32 * 1024 + n];
        float b = f32m ? ((const float*)bo)[n] : bf2f(((const u16*)bo)[n]);
        bpm[n] = acc + b;
    }
}

// ---------------------------------------------------------------------------
// K1: gates = x @ [Wr|Ww|Wm] (+bias, sigmoid on cols<64). Also emits xb (bf16 x),
// since every x element is staged here exactly once anyway.
// ---------------------------------------------------------------------------
__global__ __launch_bounds__(256) void zej_gates(
    const void* __restrict__ x, const u16* __restrict__ W3T,
    const u16* __restrict__ biasp, u16* __restrict__ gates,
    u16* __restrict__ xb, const int* __restrict__ flag)
{
    __shared__ __align__(16) u16 As[128][88];
    __shared__ __align__(16) u16 Bs[96][88];
    const int f32m = *flag;
    const int t = threadIdx.x;
    const int lane = t & 63;
    const int wv = t >> 6;
    const int row0 = blockIdx.x * 128;
    const int lm = lane & 15, lq = lane >> 4;

    f32x4 acc[2][6];
    f32x4 z = {0.f, 0.f, 0.f, 0.f};
#pragma unroll
    for (int i = 0; i < 2; i++)
#pragma unroll
        for (int j = 0; j < 6; j++) acc[i][j] = z;

    for (int k0 = 0; k0 < 1024; k0 += 64) {
#pragma unroll
        for (int c = 0; c < 4; c++) {            // A: 128x64
            int chunk = t + c * 256;
            int r = chunk >> 3, kc = (chunk & 7) * 8;
            size_t gi = (size_t)(row0 + r) * 1024 + k0 + kc;
            uint4 v;
            if (f32m) {
                const float* xf = (const float*)x;
                float4 f0 = *(const float4*)(xf + gi);
                float4 f1 = *(const float4*)(xf + gi + 4);
                v = pack8(f0, f1);
            } else {
                v = *(const uint4*)((const u16*)x + gi);
            }
            *(uint4*)&As[r][kc] = v;
            *(uint4*)(xb + gi) = v;              // bf16 x for zej_out
        }
#pragma unroll
        for (int c = 0; c < 3; c++) {            // B: 96x64
            int chunk = t + c * 256;
            int j = chunk >> 3, kc = (chunk & 7) * 8;
            *(uint4*)&Bs[j][kc] = *(const uint4*)&W3T[j * 1024 + k0 + kc];
        }
        __syncthreads();
#pragma unroll
        for (int ks = 0; ks < 2; ks++) {
            int kk = ks * 32 + lq * 8;
            bf16x8 a[2], b[6];
#pragma unroll
            for (int rt = 0; rt < 2; rt++) a[rt] = *(const bf16x8*)&As[wv * 32 + rt * 16 + lm][kk];
#pragma unroll
            for (int ct = 0; ct < 6; ct++) b[ct] = *(const bf16x8*)&Bs[ct * 16 + lm][kk];
#pragma unroll
            for (int rt = 0; rt < 2; rt++)
#pragma unroll
                for (int ct = 0; ct < 6; ct++)
                    acc[rt][ct] = mfma16(a[rt], b[ct], acc[rt][ct]);
        }
        __syncthreads();
    }
#pragma unroll
    for (int rt = 0; rt < 2; rt++) {
#pragma unroll
        for (int ct = 0; ct < 6; ct++) {
            int col = ct * 16 + lm;
            float bias = bf2f(biasp[col]);
            bool sig = (col < 64);
#pragma unroll
            for (int p = 0; p < 4; p++) {
                int R = row0 + wv * 32 + rt * 16 + lq * 4 + p;
                float v = acc[rt][ct][p] + bias;
                if (sig) v = 1.f / (1.f + __expf(-v));
                gates[R * 96 + col] = f2bf(v);
            }
        }
    }
}

// ---------------------------------------------------------------------------
// K2: per-channel linear-recurrence scan.  One wave per (b,m) channel.
// ---------------------------------------------------------------------------
__global__ __launch_bounds__(64) void zej_scan(
    const u16* __restrict__ gates, u16* __restrict__ rm)
{
    const int c = blockIdx.x;       // 0..255
    const int b = c >> 5;
    const int m = c & 31;
    const int lane = threadIdx.x;
    const u16* gb = gates + (size_t)b * SS * 96;
    const int tbase = lane * 64;

    float A = 1.f, Bc = 0.f;
    for (int i = 0; i < 64; i++) {
        int idx = (tbase + i) * 96;
        float w = bf2f(gb[idx + 32 + m]);
        float nm = bf2f(gb[idx + 64 + m]);
        float a = 1.f - w;
        Bc = a * Bc + w * nm;
        A *= a;
    }
    for (int off = 1; off < 64; off <<= 1) {
        float Ap = __shfl_up(A, off);
        float Bp = __shfl_up(Bc, off);
        if (lane >= off) { Bc = A * Bp + Bc; A = A * Ap; }
    }
    float Bprev = __shfl_up(Bc, 1);
    float mem = (lane == 0) ? 0.f : Bprev;

    for (int i = 0; i < 64; i++) {
        int idx = (tbase + i) * 96;
        float r = bf2f(gb[idx + m]);
        float w = bf2f(gb[idx + 32 + m]);
        float nm = bf2f(gb[idx + 64 + m]);
        rm[((size_t)b * SS + tbase + i) * 32 + m] = f2bf(r * mem);
        mem = (1.f - w) * mem + w * nm;
    }
}

// ---------------------------------------------------------------------------
// K4: out = tanh(xb @ Wo_x (K=1024) + rm @ Wpm (K=32) + bpm).  f32 OUTPUT.
// m97-style: global_load_lds width=16 into linear [128][64] LDS, with
// pre-swizzled global source + XOR-swizzled ds_read (byte ^= (row&7)<<4).
// ---------------------------------------------------------------------------
__global__ __launch_bounds__(256) void zej_out(
    const u16* __restrict__ xb, const u16* __restrict__ rm,
    const u16* __restrict__ WoxT, const u16* __restrict__ WpmT,
    const float* __restrict__ bpm, float* __restrict__ out)
{
    __shared__ __align__(16) u16 As[128 * 64];   // 16 KB, linear, swizzled content
    __shared__ __align__(16) u16 Bs[128 * 64];
    const int t = threadIdx.x;
    const int lane = t & 63;
    const int wv = t >> 6;
    const int wr = (wv >> 1) * 64;
    const int wc = (wv & 1) * 64;
    const int row0 = blockIdx.x * 128;
    const int n0 = blockIdx.y * 128;
    const int lm = lane & 15, lq = lane >> 4;

    f32x4 acc[4][4];
    f32x4 z = {0.f, 0.f, 0.f, 0.f};
#pragma unroll
    for (int i = 0; i < 4; i++)
#pragma unroll
        for (int j = 0; j < 4; j++) acc[i][j] = z;

    // staging geometry: one gload16 = 64 lanes * 16B = 8 rows of 128B.
    const int sr = lane >> 3;              // row within 8-row stripe
    const int slot = lane & 7;             // 16B slot within row
    const int kcs = 8 * (slot ^ sr);       // pre-swizzled source column (elems)

    for (int k0 = 0; k0 < 1024; k0 += 64) {
#pragma unroll
        for (int i = 0; i < 4; i++) {
            int ra = (wv * 4 + i) * 8 + sr;
            gload16(&As[(wv * 4 + i) * 512], xb   + (size_t)(row0 + ra) * 1024 + k0 + kcs);
            gload16(&Bs[(wv * 4 + i) * 512], WoxT + (size_t)(n0  + ra) * 1024 + k0 + kcs);
        }
        __syncthreads();                   // compiler drains vmcnt(0) here
#pragma unroll
        for (int ks = 0; ks < 2; ks++) {
            bf16x8 a[4], b[4];
#pragma unroll
            for (int rt = 0; rt < 4; rt++) {
                int R = wr + rt * 16 + lm;
                int cb = (ks * 64 + lq * 16) ^ ((R & 7) << 4);
                a[rt] = *(const bf16x8*)((const char*)As + R * 128 + cb);
            }
#pragma unroll
            for (int ct = 0; ct < 4; ct++) {
                int R = wc + ct * 16 + lm;
                int cb = (ks * 64 + lq * 16) ^ ((R & 7) << 4);
                b[ct] = *(const bf16x8*)((const char*)Bs + R * 128 + cb);
            }
#pragma unroll
            for (int rt = 0; rt < 4; rt++)
#pragma unroll
                for (int ct = 0; ct < 4; ct++)
                    acc[rt][ct] = mfma16(a[rt], b[ct], acc[rt][ct]);
        }
        __syncthreads();
    }

    // K=32 tail: rm @ WpmT. Tile rows are 64B (4 slots); swizzle within 4.
    {
        const int sr2 = lane >> 2;         // 0..15
        const int slot2 = lane & 3;
        const int kcs2 = 8 * (slot2 ^ (sr2 & 3));
#pragma unroll
        for (int i = 0; i < 2; i++) {
            int ra = (wv * 2 + i) * 16 + sr2;
            gload16(&As[(wv * 2 + i) * 512], rm   + (size_t)(row0 + ra) * 32 + kcs2);
            gload16(&Bs[(wv * 2 + i) * 512], WpmT + (size_t)(n0  + ra) * 32 + kcs2);
        }
        __syncthreads();
        bf16x8 a[4], b[4];
#pragma unroll
        for (int rt = 0; rt < 4; rt++) {
            int R = wr + rt * 16 + lm;
            a[rt] = *(const bf16x8*)((const char*)As + R * 64 + ((lq * 16) ^ ((R & 3) << 4)));
        }
#pragma unroll
        for (int ct = 0; ct < 4; ct++) {
            int R = wc + ct * 16 + lm;
            b[ct] = *(const bf16x8*)((const char*)Bs + R * 64 + ((lq * 16) ^ ((R & 3) << 4)));
        }
#pragma unroll
        for (int rt = 0; rt < 4; rt++)
#pragma unroll
            for (int ct = 0; ct < 4; ct++)
                acc[rt][ct] = mfma16(a[rt], b[ct], acc[rt][ct]);
    }

#pragma unroll
    for (int rt = 0; rt < 4; rt++) {
#pragma unroll
        for (int ct = 0; ct < 4; ct++) {
            int n = n0 + wc + ct * 16 + lm;
            float bias = bpm[n];
#pragma unroll
            for (int p = 0; p < 4; p++) {
                int R = row0 + wr + rt * 16 + lq * 4 + p;
                float v = acc[rt][ct][p] + bias;
                float e = __expf(2.f * v);          // tanh(v) = 1 - 2/(e^{2v}+1)
                out[(size_t)R * 1024 + n] = 1.f - 2.f / (e + 1.f);
            }
        }
    }
}

// ---------------------------------------------------------------------------
extern "C" void kernel_launch(void* const* d_in, const int* in_sizes, int n_in,
                              void* d_out, int out_size, void* d_ws, size_t ws_size,
                              hipStream_t stream)
{
    const void* x  = d_in[0];
    const void* Wr = d_in[1];
    const void* br = d_in[2];
    const void* Ww = d_in[3];
    const void* bw = d_in[4];
    const void* Wm = d_in[5];
    const void* bm = d_in[6];
    const void* Wp = d_in[7];
    const void* bp = d_in[8];
    const void* Wo = d_in[9];
    const void* bo = d_in[10];
    float* out = (float*)d_out;

    char* ws = (char*)d_ws;
    int* flag   = (int*)ws;                    // 4 B (pad 1 KiB)
    u16* W3T    = (u16*)(ws + 1024);           //  96*1024*2   = 196608   -> 197632
    u16* WoxT   = (u16*)(ws + 197632);         //  1024*1024*2 = 2097152  -> 2294784
    u16* WpmT   = (u16*)(ws + 2294784);        //  1024*32*2   = 65536    -> 2360320
    u16* biasp  = (u16*)(ws + 2360320);        //  96*2 -> pad 1024       -> 2361344
    float* bpm  = (float*)(ws + 2361344);      //  1024*4      = 4096     -> 2365440
    u16* gates  = (u16*)(ws + 2365440);        //  32768*96*2  = 6291456  -> 8656896
    u16* rm     = (u16*)(ws + 8656896);        //  32768*32*2  = 2097152  -> 10754048
    u16* xb     = (u16*)(ws + 10754048);       //  32768*1024*2= 67108864 -> 77862912
    // Wpm partials alias the gates buffer (freed by stream order before zej_gates):
    float* Wpm_part = (float*)(ws + 2365440);  //  16*33*1024*4 = 2162688 (< 6291456)

    zej_detect<<<1, 64, 0, stream>>>((const unsigned int*)x, flag);
    zej_pack<<<4481, 256, 0, stream>>>(Wr, Ww, Wm, Wo, br, bw, bm,
                                       W3T, WoxT, biasp, flag);
    zej_wpm_a<<<256, 256, 0, stream>>>(Wp, Wo, bp, Wpm_part, flag);
    zej_wpm_b<<<132, 256, 0, stream>>>(Wpm_part, bo, WpmT, bpm, flag);
    zej_gates<<<BS_TOT / 128, 256, 0, stream>>>(x, W3T, biasp, gates, xb, flag);
    zej_scan<<<256, 64, 0, stream>>>(gates, rm);
    zej_out<<<dim3(BS_TOT / 128, 8), 256, 0, stream>>>(xb, rm, WoxT, WpmT, bpm, out);
}

// Round 4
// 409.172 us; speedup vs baseline: 1.8843x; 1.1003x over previous
//
#include <hip/hip_runtime.h>

typedef unsigned short u16;
typedef __bf16 bf16x8 __attribute__((ext_vector_type(8)));
typedef __bf16 bf16x2 __attribute__((ext_vector_type(2)));
typedef float f32x4 __attribute__((ext_vector_type(4)));

#define BS_TOT 32768   // B*S
#define SS 4096
#define DD 1024
#define MM 32

__device__ __forceinline__ float bf2f(u16 u) {
    union { float f; unsigned int i; } c; c.i = ((unsigned int)u) << 16; return c.f;
}
__device__ __forceinline__ u16 f2bf(float f) {
    union { float f; unsigned int i; } c; c.f = f;
    unsigned int r = c.i + 0x7FFFu + ((c.i >> 16) & 1u);
    return (u16)(r >> 16);
}
__device__ __forceinline__ f32x4 mfma16(bf16x8 a, bf16x8 b, f32x4 c) {
    return __builtin_amdgcn_mfma_f32_16x16x32_bf16(a, b, c, 0, 0, 0);
}
__device__ __forceinline__ u16 cvt_in(const void* p, size_t i, int f32m) {
    return f32m ? f2bf(((const float*)p)[i]) : ((const u16*)p)[i];
}
// pack 2 f32 -> bf16x2 word; compiler fuses pairs to v_cvt_pk_bf16_f32
__device__ __forceinline__ unsigned cvt2(float x, float y) {
    bf16x2 p; p[0] = (__bf16)x; p[1] = (__bf16)y;
    union { bf16x2 v; unsigned u; } c; c.v = p; return c.u;
}
__device__ __forceinline__ uint4 pack8c(float4 a, float4 b) {
    uint4 v;
    v.x = cvt2(a.x, a.y); v.y = cvt2(a.z, a.w);
    v.z = cvt2(b.x, b.y); v.w = cvt2(b.z, b.w);
    return v;
}
// async global->LDS, 16B per lane. LDS dest is wave-uniform base + lane*16.
__device__ __forceinline__ void gload16(u16* l, const u16* g) {
    __builtin_amdgcn_global_load_lds(
        (const __attribute__((address_space(1))) unsigned int*)(g),
        (__attribute__((address_space(3))) unsigned int*)(l),
        16, 0, 0);
}
__device__ __forceinline__ unsigned u4get(const uint4& v, int idx) {
    return idx == 0 ? v.x : idx == 1 ? v.y : idx == 2 ? v.z : v.w;
}
// element j (0..15) of 16 u16 packed in two uint4 (j must be compile-time)
__device__ __forceinline__ u16 elem16(const uint4& a, const uint4& b, int j) {
    unsigned w = (j < 8) ? u4get(a, j >> 1) : u4get(b, (j - 8) >> 1);
    return (u16)((j & 1) ? (w >> 16) : (w & 0xFFFFu));
}

// ---------------------------------------------------------------------------
// K-1: dtype detector (insurance; evidence says inputs are f32). flag=1 -> f32.
// ---------------------------------------------------------------------------
__global__ __launch_bounds__(64) void zej_detect(const unsigned int* __restrict__ xw,
                                                 int* __restrict__ flag)
{
    int lane = threadIdx.x;
    int cnt = 0;
#pragma unroll
    for (int i = 0; i < 16; i++) {
        unsigned int w = xw[lane * 16 + i];
        unsigned int e = (w >> 7) & 0xFFu;
        cnt += (e >= 110u && e <= 135u) ? 1 : 0;
    }
#pragma unroll
    for (int off = 32; off > 0; off >>= 1) cnt += __shfl_down(cnt, off);
    if (lane == 0) *flag = (cnt < 512) ? 1 : 0;
}

// ---------------------------------------------------------------------------
// K0: pack small weights/biases: W3T[96][1024] = [Wr|Ww|Wm]^T, biasp[0:96].
// ---------------------------------------------------------------------------
__global__ __launch_bounds__(256) void zej_pack(
    const void* __restrict__ Wr, const void* __restrict__ Ww, const void* __restrict__ Wm,
    const void* __restrict__ br, const void* __restrict__ bw, const void* __restrict__ bm,
    u16* __restrict__ W3T, u16* __restrict__ biasp, const int* __restrict__ flag)
{
    const int f32m = *flag;
    int i = blockIdx.x * 256 + threadIdx.x;
    if (i < 98304) {            // W3T
        int j = i >> 10, k = i & 1023;
        W3T[i] = (j < 32) ? cvt_in(Wr, (size_t)k * 32 + j, f32m)
               : (j < 64) ? cvt_in(Ww, (size_t)k * 32 + (j - 32), f32m)
                          : cvt_in(Wm, (size_t)k * 32 + (j - 64), f32m);
        return;
    }
    i -= 98304;
    if (i < 96) {
        biasp[i] = (i < 32) ? cvt_in(br, i, f32m)
                 : (i < 64) ? cvt_in(bw, i - 32, f32m)
                            : cvt_in(bm, i - 64, f32m);
    }
}

// ---------------------------------------------------------------------------
// K0t: WoxT[n][k] = Wo[k][n] (k<1024) via LDS tile transpose, coalesced both sides.
// Grid 256 = (kb 0..15) x (nb 0..15), 64x64 tiles.
// ---------------------------------------------------------------------------
__global__ __launch_bounds__(256) void zej_packT(
    const void* __restrict__ Wo, u16* __restrict__ WoxT, const int* __restrict__ flag)
{
    __shared__ float tile[64][65];
    const int f32m = *flag;
    const int t = threadIdx.x;
    const int kb = blockIdx.x & 15, nb = blockIdx.x >> 4;
    const int k0 = kb * 64, n0 = nb * 64;
#pragma unroll
    for (int i = 0; i < 16; i++) {           // read Wo rows, coalesced over n
        int idx = i * 256 + t;
        int r = idx >> 6, c = idx & 63;      // r=k-off, c=n-off
        size_t gi = (size_t)(k0 + r) * 1024 + n0 + c;
        tile[r][c] = f32m ? ((const float*)Wo)[gi] : bf2f(((const u16*)Wo)[gi]);
    }
    __syncthreads();
#pragma unroll
    for (int i = 0; i < 16; i++) {           // write WoxT rows, coalesced over k
        int idx = i * 256 + t;
        int nn = idx >> 6, kk = idx & 63;
        WoxT[(size_t)(n0 + nn) * 1024 + k0 + kk] = f2bf(tile[kk][nn]);
    }
}

// ---------------------------------------------------------------------------
// K0b-A: partial Wpm.  Grid 256 = (nb 0..15) x (kb 0..15).
// part[kb][m][nb*64+n] = sum_{dd<64} Wp[m][kb*64+dd]*Wo_m[kb*64+dd][n], bp row at m=32.
// part aliases the gtc buffer (freed by stream order before zej_gates).
// ---------------------------------------------------------------------------
__global__ __launch_bounds__(256) void zej_wpm_a(
    const void* __restrict__ Wp, const void* __restrict__ Wo,
    const void* __restrict__ bp,
    float* __restrict__ part, const int* __restrict__ flag)
{
    __shared__ float wpc[64 * 33];   // [dd][m], stride 33 -> conflict-free
    __shared__ float bpc[64];
    const int f32m = *flag;
    const int t = threadIdx.x;
    const int nb = blockIdx.x & 15;
    const int kb = blockIdx.x >> 4;
    const int d0 = kb * 64;

    for (int i = t; i < 2048; i += 256) {
        int m = i >> 6, dd = i & 63;
        float v = f32m ? ((const float*)Wp)[m * 1024 + d0 + dd]
                       : bf2f(((const u16*)Wp)[m * 1024 + d0 + dd]);
        wpc[dd * 33 + m] = v;
    }
    if (t < 64)
        bpc[t] = f32m ? ((const float*)bp)[d0 + t] : bf2f(((const u16*)bp)[d0 + t]);
    __syncthreads();

    const int n = nb * 64 + (t & 63);
    const int g = t >> 6;
    float acc[8];
#pragma unroll
    for (int j = 0; j < 8; j++) acc[j] = 0.f;
    float bacc = 0.f;

    for (int dd = 0; dd < 64; dd++) {
        float w = f32m ? ((const float*)Wo)[(size_t)(1024 + d0 + dd) * 1024 + n]
                       : bf2f(((const u16*)Wo)[(size_t)(1024 + d0 + dd) * 1024 + n]);
        const float* wp8 = &wpc[dd * 33 + g * 8];
#pragma unroll
        for (int j = 0; j < 8; j++) acc[j] += wp8[j] * w;
        if (g == 0) bacc += bpc[dd] * w;
    }
    float* pk = part + (size_t)kb * 33792;    // 33*1024
#pragma unroll
    for (int j = 0; j < 8; j++) pk[(g * 8 + j) * 1024 + n] = acc[j];
    if (g == 0) pk[32 * 1024 + n] = bacc;
}

// ---------------------------------------------------------------------------
// K0b-B: reduce 16 partials -> WpmT[n][32] bf16, bpm[n] f32 (+bo).
// ---------------------------------------------------------------------------
__global__ __launch_bounds__(256) void zej_wpm_b(
    const float* __restrict__ part, const void* __restrict__ bo,
    u16* __restrict__ WpmT, float* __restrict__ bpm, const int* __restrict__ flag)
{
    const int f32m = *flag;
    const int t = threadIdx.x;
    const int bid = blockIdx.x;
    if (bid < 128) {
        int m = bid >> 2;
        int n = (bid & 3) * 256 + t;
        float acc = 0.f;
#pragma unroll
        for (int kb = 0; kb < 16; kb++) acc += part[(size_t)kb * 33792 + m * 1024 + n];
        WpmT[(size_t)n * 32 + m] = f2bf(acc);
    } else {
        int n = (bid - 128) * 256 + t;
        float acc = 0.f;
#pragma unroll
        for (int kb = 0; kb < 16; kb++) acc += part[(size_t)kb * 33792 + 32 * 1024 + n];
        float b = f32m ? ((const float*)bo)[n] : bf2f(((const u16*)bo)[n]);
        bpm[n] = acc + b;
    }
}

// ---------------------------------------------------------------------------
// K1: gates = x @ [Wr|Ww|Wm] (+bias, sigmoid on cols<64), written CHANNEL-MAJOR
// gtc[96][32768] for the scan. Also emits xb (bf16 x).
// ---------------------------------------------------------------------------
__global__ __launch_bounds__(256) void zej_gates(
    const void* __restrict__ x, const u16* __restrict__ W3T,
    const u16* __restrict__ biasp, u16* __restrict__ gtc,
    u16* __restrict__ xb, const int* __restrict__ flag)
{
    __shared__ __align__(16) u16 As[128][88];
    __shared__ __align__(16) u16 Bs[96][88];
    const int f32m = *flag;
    const int t = threadIdx.x;
    const int lane = t & 63;
    const int wv = t >> 6;
    const int row0 = blockIdx.x * 128;
    const int lm = lane & 15, lq = lane >> 4;

    f32x4 acc[2][6];
    f32x4 z = {0.f, 0.f, 0.f, 0.f};
#pragma unroll
    for (int i = 0; i < 2; i++)
#pragma unroll
        for (int j = 0; j < 6; j++) acc[i][j] = z;

    for (int k0 = 0; k0 < 1024; k0 += 64) {
#pragma unroll
        for (int c = 0; c < 4; c++) {            // A: 128x64
            int chunk = t + c * 256;
            int r = chunk >> 3, kc = (chunk & 7) * 8;
            size_t gi = (size_t)(row0 + r) * 1024 + k0 + kc;
            uint4 v;
            if (f32m) {
                const float* xf = (const float*)x;
                float4 f0 = *(const float4*)(xf + gi);
                float4 f1 = *(const float4*)(xf + gi + 4);
                v = pack8c(f0, f1);
            } else {
                v = *(const uint4*)((const u16*)x + gi);
            }
            *(uint4*)&As[r][kc] = v;
            *(uint4*)(xb + gi) = v;              // bf16 x for zej_out
        }
#pragma unroll
        for (int c = 0; c < 3; c++) {            // B: 96x64
            int chunk = t + c * 256;
            int j = chunk >> 3, kc = (chunk & 7) * 8;
            *(uint4*)&Bs[j][kc] = *(const uint4*)&W3T[j * 1024 + k0 + kc];
        }
        __syncthreads();
#pragma unroll
        for (int ks = 0; ks < 2; ks++) {
            int kk = ks * 32 + lq * 8;
            bf16x8 a[2], b[6];
#pragma unroll
            for (int rt = 0; rt < 2; rt++) a[rt] = *(const bf16x8*)&As[wv * 32 + rt * 16 + lm][kk];
#pragma unroll
            for (int ct = 0; ct < 6; ct++) b[ct] = *(const bf16x8*)&Bs[ct * 16 + lm][kk];
#pragma unroll
            for (int rt = 0; rt < 2; rt++)
#pragma unroll
                for (int ct = 0; ct < 6; ct++)
                    acc[rt][ct] = mfma16(a[rt], b[ct], acc[rt][ct]);
        }
        __syncthreads();
    }
#pragma unroll
    for (int rt = 0; rt < 2; rt++) {
#pragma unroll
        for (int ct = 0; ct < 6; ct++) {
            int col = ct * 16 + lm;
            float bias = bf2f(biasp[col]);
            bool sig = (col < 64);
#pragma unroll
            for (int p = 0; p < 4; p++) {
                int R = row0 + wv * 32 + rt * 16 + lq * 4 + p;
                float v = acc[rt][ct][p] + bias;
                if (sig) v = 1.f / (1.f + __expf(-v));
                gtc[(size_t)col * BS_TOT + R] = f2bf(v);
            }
        }
    }
}

// ---------------------------------------------------------------------------
// K2: scan, channel-major. Block = (b,m), 256 threads x 16 t's each.
// Coalesced uint4 loads; two-level (shfl + LDS) exclusive scan of (A,B);
// rm written channel-major rmc[m][R] coalesced.
// ---------------------------------------------------------------------------
__global__ __launch_bounds__(256) void zej_scan(
    const u16* __restrict__ gtc, u16* __restrict__ rmc)
{
    __shared__ float sA[4], sB[4];
    const int c = blockIdx.x;       // 0..255
    const int b = c >> 5;
    const int m = c & 31;
    const int t = threadIdx.x;
    const int lane = t & 63;
    const int wv = t >> 6;
    const size_t base = (size_t)b * SS;
    const u16* gr  = gtc + (size_t)( 0 + m) * BS_TOT + base;
    const u16* gw  = gtc + (size_t)(32 + m) * BS_TOT + base;
    const u16* gnm = gtc + (size_t)(64 + m) * BS_TOT + base;
    const int i0 = t * 16;

    uint4 w0 = *(const uint4*)(gw + i0);
    uint4 w1 = *(const uint4*)(gw + i0 + 8);
    uint4 n0 = *(const uint4*)(gnm + i0);
    uint4 n1 = *(const uint4*)(gnm + i0 + 8);

    // local segment combine over 16 t's
    float A = 1.f, Bc = 0.f;
#pragma unroll
    for (int j = 0; j < 16; j++) {
        float w  = bf2f(elem16(w0, w1, j));
        float nm = bf2f(elem16(n0, n1, j));
        float a = 1.f - w;
        Bc = a * Bc + w * nm;
        A *= a;
    }
    // inclusive Kogge-Stone scan within wave
    float Ai = A, Bi = Bc;
    for (int off = 1; off < 64; off <<= 1) {
        float Ap = __shfl_up(Ai, off);
        float Bp = __shfl_up(Bi, off);
        if (lane >= off) { Bi = Ai * Bp + Bi; Ai = Ai * Ap; }
    }
    if (lane == 63) { sA[wv] = Ai; sB[wv] = Bi; }
    __syncthreads();
    // exclusive prefix over waves (<=3 composes, LDS broadcast)
    float Aw = 1.f, Bw = 0.f;
    for (int k = 0; k < wv; k++) {
        float a2 = sA[k];
        Bw = a2 * Bw + sB[k];
        Aw = Aw * a2;
    }
    // exclusive within wave
    float Ae = __shfl_up(Ai, 1);
    float Be = __shfl_up(Bi, 1);
    if (lane == 0) { Ae = 1.f; Be = 0.f; }
    // mem0 = 0 -> starting mem = B of (wave-prefix then lane-prefix)
    float mem = Ae * Bw + Be;

    uint4 r0 = *(const uint4*)(gr + i0);
    uint4 r1 = *(const uint4*)(gr + i0 + 8);
    u16 o[16];
#pragma unroll
    for (int j = 0; j < 16; j++) {
        float r  = bf2f(elem16(r0, r1, j));
        float w  = bf2f(elem16(w0, w1, j));
        float nm = bf2f(elem16(n0, n1, j));
        o[j] = f2bf(r * mem);
        mem = (1.f - w) * mem + w * nm;
    }
    u16* dst = rmc + (size_t)m * BS_TOT + base + i0;
    *(uint4*)dst       = *(uint4*)&o[0];
    *(uint4*)(dst + 8) = *(uint4*)&o[8];
}

// ---------------------------------------------------------------------------
// K2t: transpose rmc[32][32768] -> rm[32768][32] (row-major for zej_out tail).
// Grid 256, tile 128R x 32m via LDS.
// ---------------------------------------------------------------------------
__global__ __launch_bounds__(256) void zej_rmt(
    const u16* __restrict__ rmc, u16* __restrict__ rm)
{
    __shared__ __align__(16) u16 tile[32][136];
    const int t = threadIdx.x;
    const int R0 = blockIdx.x * 128;
#pragma unroll
    for (int c = 0; c < 2; c++) {            // load: 32 rows x 128 elems
        int idx = t + c * 256;
        int m = idx >> 4, kq = (idx & 15) * 8;
        *(uint4*)&tile[m][kq] = *(const uint4*)&rmc[(size_t)m * BS_TOT + R0 + kq];
    }
    __syncthreads();
#pragma unroll
    for (int c = 0; c < 2; c++) {            // write: 128 rows x 32 m
        int idx = t + c * 256;               // r varies fastest across lanes
        int r = idx & 127, mq = (idx >> 7) * 8;
        u16 tmp[8];
#pragma unroll
        for (int j = 0; j < 8; j++) tmp[j] = tile[mq + j][r];
        *(uint4*)&rm[(size_t)(R0 + r) * 32 + mq] = *(uint4*)tmp;
    }
}

// ---------------------------------------------------------------------------
// K4: out = tanh(xb @ Wo_x (K=1024) + rm @ Wpm (K=32) + bpm).  f32 OUTPUT.
// 1-D grid with XCD-chunk swizzle: each XCD owns 32 row-blocks x all 8 n-blocks
// (n fast) so the 8 blocks sharing an xb panel are co-resident on one XCD.
// ---------------------------------------------------------------------------
__global__ __launch_bounds__(256) void zej_out(
    const u16* __restrict__ xb, const u16* __restrict__ rm,
    const u16* __restrict__ WoxT, const u16* __restrict__ WpmT,
    const float* __restrict__ bpm, float* __restrict__ out)
{
    __shared__ __align__(16) u16 As[128 * 64];   // 16 KB, linear, swizzled content
    __shared__ __align__(16) u16 Bs[128 * 64];
    const int t = threadIdx.x;
    const int lane = t & 63;
    const int wv = t >> 6;
    const int wr = (wv >> 1) * 64;
    const int wc = (wv & 1) * 64;
    const int bid = blockIdx.x;                  // 0..2047
    const int lin = (bid & 7) * 256 + (bid >> 3);
    const int row0 = (lin >> 3) * 128;
    const int n0 = (lin & 7) * 128;
    const int lm = lane & 15, lq = lane >> 4;

    f32x4 acc[4][4];
    f32x4 z = {0.f, 0.f, 0.f, 0.f};
#pragma unroll
    for (int i = 0; i < 4; i++)
#pragma unroll
        for (int j = 0; j < 4; j++) acc[i][j] = z;

    // staging geometry: one gload16 = 64 lanes * 16B = 8 rows of 128B.
    const int sr = lane >> 3;              // row within 8-row stripe
    const int slot = lane & 7;             // 16B slot within row
    const int kcs = 8 * (slot ^ sr);       // pre-swizzled source column (elems)

    for (int k0 = 0; k0 < 1024; k0 += 64) {
#pragma unroll
        for (int i = 0; i < 4; i++) {
            int ra = (wv * 4 + i) * 8 + sr;
            gload16(&As[(wv * 4 + i) * 512], xb   + (size_t)(row0 + ra) * 1024 + k0 + kcs);
            gload16(&Bs[(wv * 4 + i) * 512], WoxT + (size_t)(n0  + ra) * 1024 + k0 + kcs);
        }
        __syncthreads();                   // compiler drains vmcnt(0) here
#pragma unroll
        for (int ks = 0; ks < 2; ks++) {
            bf16x8 a[4], b[4];
#pragma unroll
            for (int rt = 0; rt < 4; rt++) {
                int R = wr + rt * 16 + lm;
                int cb = (ks * 64 + lq * 16) ^ ((R & 7) << 4);
                a[rt] = *(const bf16x8*)((const char*)As + R * 128 + cb);
            }
#pragma unroll
            for (int ct = 0; ct < 4; ct++) {
                int R = wc + ct * 16 + lm;
                int cb = (ks * 64 + lq * 16) ^ ((R & 7) << 4);
                b[ct] = *(const bf16x8*)((const char*)Bs + R * 128 + cb);
            }
#pragma unroll
            for (int rt = 0; rt < 4; rt++)
#pragma unroll
                for (int ct = 0; ct < 4; ct++)
                    acc[rt][ct] = mfma16(a[rt], b[ct], acc[rt][ct]);
        }
        __syncthreads();
    }

    // K=32 tail: rm @ WpmT. Tile rows are 64B (4 slots); swizzle within 4.
    {
        const int sr2 = lane >> 2;         // 0..15
        const int slot2 = lane & 3;
        const int kcs2 = 8 * (slot2 ^ (sr2 & 3));
#pragma unroll
        for (int i = 0; i < 2; i++) {
            int ra = (wv * 2 + i) * 16 + sr2;
            gload16(&As[(wv * 2 + i) * 512], rm   + (size_t)(row0 + ra) * 32 + kcs2);
            gload16(&Bs[(wv * 2 + i) * 512], WpmT + (size_t)(n0  + ra) * 32 + kcs2);
        }
        __syncthreads();
        bf16x8 a[4], b[4];
#pragma unroll
        for (int rt = 0; rt < 4; rt++) {
            int R = wr + rt * 16 + lm;
            a[rt] = *(const bf16x8*)((const char*)As + R * 64 + ((lq * 16) ^ ((R & 3) << 4)));
        }
#pragma unroll
        for (int ct = 0; ct < 4; ct++) {
            int R = wc + ct * 16 + lm;
            b[ct] = *(const bf16x8*)((const char*)Bs + R * 64 + ((lq * 16) ^ ((R & 3) << 4)));
        }
#pragma unroll
        for (int rt = 0; rt < 4; rt++)
#pragma unroll
            for (int ct = 0; ct < 4; ct++)
                acc[rt][ct] = mfma16(a[rt], b[ct], acc[rt][ct]);
    }

#pragma unroll
    for (int rt = 0; rt < 4; rt++) {
#pragma unroll
        for (int ct = 0; ct < 4; ct++) {
            int n = n0 + wc + ct * 16 + lm;
            float bias = bpm[n];
#pragma unroll
            for (int p = 0; p < 4; p++) {
                int R = row0 + wr + rt * 16 + lq * 4 + p;
                float v = acc[rt][ct][p] + bias;
                float e = __expf(2.f * v);          // tanh(v) = 1 - 2/(e^{2v}+1)
                out[(size_t)R * 1024 + n] = 1.f - 2.f / (e + 1.f);
            }
        }
    }
}

// ---------------------------------------------------------------------------
extern "C" void kernel_launch(void* const* d_in, const int* in_sizes, int n_in,
                              void* d_out, int out_size, void* d_ws, size_t ws_size,
                              hipStream_t stream)
{
    const void* x  = d_in[0];
    const void* Wr = d_in[1];
    const void* br = d_in[2];
    const void* Ww = d_in[3];
    const void* bw = d_in[4];
    const void* Wm = d_in[5];
    const void* bm = d_in[6];
    const void* Wp = d_in[7];
    const void* bp = d_in[8];
    const void* Wo = d_in[9];
    const void* bo = d_in[10];
    float* out = (float*)d_out;

    char* ws = (char*)d_ws;
    int* flag   = (int*)ws;                    // 4 B (pad 1 KiB)
    u16* W3T    = (u16*)(ws + 1024);           //  96*1024*2   = 196608   -> 197632
    u16* WoxT   = (u16*)(ws + 197632);         //  1024*1024*2 = 2097152  -> 2294784
    u16* WpmT   = (u16*)(ws + 2294784);        //  1024*32*2   = 65536    -> 2360320
    u16* biasp  = (u16*)(ws + 2360320);        //  96*2 -> pad 1024       -> 2361344
    float* bpm  = (float*)(ws + 2361344);      //  1024*4      = 4096     -> 2365440
    u16* gtc    = (u16*)(ws + 2365440);        //  96*32768*2  = 6291456  -> 8656896
    u16* rmc    = (u16*)(ws + 8656896);        //  32*32768*2  = 2097152  -> 10754048
    u16* rm     = (u16*)(ws + 10754048);       //  32768*32*2  = 2097152  -> 12851200
    u16* xb     = (u16*)(ws + 12851200);       //  32768*1024*2= 67108864 -> 79960064
    // Wpm partials alias the gtc buffer (freed by stream order before zej_gates):
    float* Wpm_part = (float*)(ws + 2365440);  //  16*33*1024*4 = 2162688 (< 6291456)

    zej_detect<<<1, 64, 0, stream>>>((const unsigned int*)x, flag);
    zej_pack<<<385, 256, 0, stream>>>(Wr, Ww, Wm, br, bw, bm, W3T, biasp, flag);
    zej_packT<<<256, 256, 0, stream>>>(Wo, WoxT, flag);
    zej_wpm_a<<<256, 256, 0, stream>>>(Wp, Wo, bp, Wpm_part, flag);
    zej_wpm_b<<<132, 256, 0, stream>>>(Wpm_part, bo, WpmT, bpm, flag);
    zej_gates<<<BS_TOT / 128, 256, 0, stream>>>(x, W3T, biasp, gtc, xb, flag);
    zej_scan<<<256, 256, 0, stream>>>(gtc, rmc);
    zej_rmt<<<256, 256, 0, stream>>>(rmc, rm);
    zej_out<<<2048, 256, 0, stream>>>(xb, rm, WoxT, WpmT, bpm, out);
}

// Round 5
// 403.450 us; speedup vs baseline: 1.9110x; 1.0142x over previous
//
#include <hip/hip_runtime.h>

typedef unsigned short u16;
typedef __bf16 bf16x8 __attribute__((ext_vector_type(8)));
typedef __bf16 bf16x2 __attribute__((ext_vector_type(2)));
typedef float f32x4 __attribute__((ext_vector_type(4)));

#define BS_TOT 32768   // B*S
#define SS 4096
#define DD 1024
#define MM 32

__device__ __forceinline__ float bf2f(u16 u) {
    union { float f; unsigned int i; } c; c.i = ((unsigned int)u) << 16; return c.f;
}
__device__ __forceinline__ u16 f2bf(float f) {
    union { float f; unsigned int i; } c; c.f = f;
    unsigned int r = c.i + 0x7FFFu + ((c.i >> 16) & 1u);
    return (u16)(r >> 16);
}
__device__ __forceinline__ f32x4 mfma16(bf16x8 a, bf16x8 b, f32x4 c) {
    return __builtin_amdgcn_mfma_f32_16x16x32_bf16(a, b, c, 0, 0, 0);
}
__device__ __forceinline__ u16 cvt_in(const void* p, size_t i, int f32m) {
    return f32m ? f2bf(((const float*)p)[i]) : ((const u16*)p)[i];
}
// pack 2 f32 -> bf16x2 word; compiler fuses pairs to v_cvt_pk_bf16_f32
__device__ __forceinline__ unsigned cvt2(float x, float y) {
    bf16x2 p; p[0] = (__bf16)x; p[1] = (__bf16)y;
    union { bf16x2 v; unsigned u; } c; c.v = p; return c.u;
}
__device__ __forceinline__ uint4 pack8c(float4 a, float4 b) {
    uint4 v;
    v.x = cvt2(a.x, a.y); v.y = cvt2(a.z, a.w);
    v.z = cvt2(b.x, b.y); v.w = cvt2(b.z, b.w);
    return v;
}
// async global->LDS, 16B per lane. LDS dest is wave-uniform base + lane*16.
__device__ __forceinline__ void gload16(u16* l, const u16* g) {
    __builtin_amdgcn_global_load_lds(
        (const __attribute__((address_space(1))) unsigned int*)(g),
        (__attribute__((address_space(3))) unsigned int*)(l),
        16, 0, 0);
}
__device__ __forceinline__ unsigned u4get(const uint4& v, int idx) {
    return idx == 0 ? v.x : idx == 1 ? v.y : idx == 2 ? v.z : v.w;
}
// element j (0..15) of 16 u16 packed in two uint4 (j must be compile-time)
__device__ __forceinline__ u16 elem16(const uint4& a, const uint4& b, int j) {
    unsigned w = (j < 8) ? u4get(a, j >> 1) : u4get(b, (j - 8) >> 1);
    return (u16)((j & 1) ? (w >> 16) : (w & 0xFFFFu));
}

// Per-block dtype self-detect (replaces separate detect kernel + flag buffer).
// For f32 N(0,1) data bits 14..7 of each word are ~uniform (~10% in [110,135]);
// for bf16-pair data they are a bf16 exponent (~99.9% in range). 1 -> f32.
// Must be called by all 256 threads before any block-divergent branch.
__device__ __forceinline__ int block_detect_f32(const unsigned int* xw) {
    __shared__ int s_cnt;
    if (threadIdx.x == 0) s_cnt = 0;
    __syncthreads();
    int cnt = 0;
#pragma unroll
    for (int i = 0; i < 4; i++) {
        unsigned int w = xw[threadIdx.x * 4 + i];
        unsigned int e = (w >> 7) & 0xFFu;
        cnt += (e >= 110u && e <= 135u) ? 1 : 0;
    }
#pragma unroll
    for (int off = 32; off > 0; off >>= 1) cnt += __shfl_down(cnt, off);
    if ((threadIdx.x & 63) == 0) atomicAdd(&s_cnt, cnt);
    __syncthreads();
    return (s_cnt < 512) ? 1 : 0;
}

// ---------------------------------------------------------------------------
// K0 zej_prep: merged weight prep. Grid 769:
//   [0,385):   W3T[96][1024]=[Wr|Ww|Wm]^T + biasp[0:96]
//   [385,641): WoxT[n][k]=Wo[k][n] (k<1024) via LDS tile transpose
//   [641,769): wpm_a partials: part[kb][m][nb*64+n] (kb<8, 128-deep chunks),
//              bp row at m=32.  part aliases rmc (dead until zej_scan).
// ---------------------------------------------------------------------------
__global__ __launch_bounds__(256) void zej_prep(
    const void* __restrict__ x,
    const void* __restrict__ Wr, const void* __restrict__ Ww, const void* __restrict__ Wm,
    const void* __restrict__ Wp, const void* __restrict__ Wo,
    const void* __restrict__ br, const void* __restrict__ bw, const void* __restrict__ bm,
    const void* __restrict__ bp,
    u16* __restrict__ W3T, u16* __restrict__ WoxT, u16* __restrict__ biasp,
    float* __restrict__ part)
{
    __shared__ float tile[64][65];     // packT
    __shared__ float wpc[128 * 33];    // wpm_a
    __shared__ float bpc[128];
    const int f32m = block_detect_f32((const unsigned int*)x);
    const int t = threadIdx.x;
    const int bid = blockIdx.x;

    if (bid < 385) {                   // ---- pack W3T + biasp ----
        int i = bid * 256 + t;
        if (i < 98304) {
            int j = i >> 10, k = i & 1023;
            W3T[i] = (j < 32) ? cvt_in(Wr, (size_t)k * 32 + j, f32m)
                   : (j < 64) ? cvt_in(Ww, (size_t)k * 32 + (j - 32), f32m)
                              : cvt_in(Wm, (size_t)k * 32 + (j - 64), f32m);
            return;
        }
        i -= 98304;
        if (i < 96) {
            biasp[i] = (i < 32) ? cvt_in(br, i, f32m)
                     : (i < 64) ? cvt_in(bw, i - 32, f32m)
                                : cvt_in(bm, i - 64, f32m);
        }
        return;
    }
    if (bid < 641) {                   // ---- packT: WoxT ----
        int b2 = bid - 385;
        const int kb = b2 & 15, nb = b2 >> 4;
        const int k0 = kb * 64, n0 = nb * 64;
#pragma unroll
        for (int i = 0; i < 16; i++) {
            int idx = i * 256 + t;
            int r = idx >> 6, c = idx & 63;
            size_t gi = (size_t)(k0 + r) * 1024 + n0 + c;
            tile[r][c] = f32m ? ((const float*)Wo)[gi] : bf2f(((const u16*)Wo)[gi]);
        }
        __syncthreads();
#pragma unroll
        for (int i = 0; i < 16; i++) {
            int idx = i * 256 + t;
            int nn = idx >> 6, kk = idx & 63;
            WoxT[(size_t)(n0 + nn) * 1024 + k0 + kk] = f2bf(tile[kk][nn]);
        }
        return;
    }
    {                                  // ---- wpm_a: 8 K-chunks of 128 ----
        int b2 = bid - 641;            // 0..127
        const int nb = b2 & 15;
        const int kb = b2 >> 4;        // 0..7
        const int d0 = kb * 128;

        for (int i = t; i < 4096; i += 256) {
            int m = i >> 7, dd = i & 127;
            float v = f32m ? ((const float*)Wp)[m * 1024 + d0 + dd]
                           : bf2f(((const u16*)Wp)[m * 1024 + d0 + dd]);
            wpc[dd * 33 + m] = v;
        }
        if (t < 128)
            bpc[t] = f32m ? ((const float*)bp)[d0 + t] : bf2f(((const u16*)bp)[d0 + t]);
        __syncthreads();

        const int n = nb * 64 + (t & 63);
        const int g = t >> 6;
        float acc[8];
#pragma unroll
        for (int j = 0; j < 8; j++) acc[j] = 0.f;
        float bacc = 0.f;

        for (int dd = 0; dd < 128; dd++) {
            float w = f32m ? ((const float*)Wo)[(size_t)(1024 + d0 + dd) * 1024 + n]
                           : bf2f(((const u16*)Wo)[(size_t)(1024 + d0 + dd) * 1024 + n]);
            const float* wp8 = &wpc[dd * 33 + g * 8];
#pragma unroll
            for (int j = 0; j < 8; j++) acc[j] += wp8[j] * w;
            if (g == 0) bacc += bpc[dd] * w;
        }
        float* pk = part + (size_t)kb * 33792;    // 33*1024
#pragma unroll
        for (int j = 0; j < 8; j++) pk[(g * 8 + j) * 1024 + n] = acc[j];
        if (g == 0) pk[32 * 1024 + n] = bacc;
    }
}

// ---------------------------------------------------------------------------
// K1 zej_gates: grid 644.
//   [0,512): gates = x @ [Wr|Ww|Wm] (+bias, sigmoid cols<64), 64-row tiles
//            (2-3 blocks/CU vs old 1). gtc written CHANNEL-MAJOR via LDS
//            transpose (coalesced 128B runs, no 2B scatter). Also emits xb.
//   [512,644): wpm_b reduce: part -> WpmT[n][32] bf16, bpm[n]=sum+bo.
// ---------------------------------------------------------------------------
__global__ __launch_bounds__(256) void zej_gates(
    const void* __restrict__ x, const u16* __restrict__ W3T,
    const u16* __restrict__ biasp,
    const float* __restrict__ part, const void* __restrict__ bo,
    u16* __restrict__ gtc, u16* __restrict__ xb,
    u16* __restrict__ WpmT, float* __restrict__ bpm)
{
    __shared__ __align__(16) u16 As[64][88];
    __shared__ __align__(16) u16 Bs[96][88];
    __shared__ __align__(16) u16 Ts[96][72];
    const int f32m = block_detect_f32((const unsigned int*)x);
    const int t = threadIdx.x;
    const int bid = blockIdx.x;

    if (bid >= 512) {                  // ---- wpm_b ----
        int b2 = bid - 512;
        if (b2 < 128) {
            int m = b2 >> 2;
            int n = (b2 & 3) * 256 + t;
            float acc = 0.f;
#pragma unroll
            for (int kb = 0; kb < 8; kb++) acc += part[(size_t)kb * 33792 + m * 1024 + n];
            WpmT[(size_t)n * 32 + m] = f2bf(acc);
        } else {
            int n = (b2 - 128) * 256 + t;
            float acc = 0.f;
#pragma unroll
            for (int kb = 0; kb < 8; kb++) acc += part[(size_t)kb * 33792 + 32 * 1024 + n];
            float b = f32m ? ((const float*)bo)[n] : bf2f(((const u16*)bo)[n]);
            bpm[n] = acc + b;
        }
        return;
    }

    const int lane = t & 63;
    const int wv = t >> 6;
    const int row0 = bid * 64;
    const int lm = lane & 15, lq = lane >> 4;

    f32x4 acc[6];
    f32x4 z = {0.f, 0.f, 0.f, 0.f};
#pragma unroll
    for (int j = 0; j < 6; j++) acc[j] = z;

    for (int k0 = 0; k0 < 1024; k0 += 64) {
#pragma unroll
        for (int c = 0; c < 2; c++) {            // A: 64x64
            int chunk = t + c * 256;
            int r = chunk >> 3, kc = (chunk & 7) * 8;
            size_t gi = (size_t)(row0 + r) * 1024 + k0 + kc;
            uint4 v;
            if (f32m) {
                const float* xf = (const float*)x;
                float4 f0 = *(const float4*)(xf + gi);
                float4 f1 = *(const float4*)(xf + gi + 4);
                v = pack8c(f0, f1);
            } else {
                v = *(const uint4*)((const u16*)x + gi);
            }
            *(uint4*)&As[r][kc] = v;
            *(uint4*)(xb + gi) = v;              // bf16 x for zej_out
        }
#pragma unroll
        for (int c = 0; c < 3; c++) {            // B: 96x64
            int chunk = t + c * 256;
            int j = chunk >> 3, kc = (chunk & 7) * 8;
            *(uint4*)&Bs[j][kc] = *(const uint4*)&W3T[j * 1024 + k0 + kc];
        }
        __syncthreads();
#pragma unroll
        for (int ks = 0; ks < 2; ks++) {
            int kk = ks * 32 + lq * 8;
            bf16x8 a = *(const bf16x8*)&As[wv * 16 + lm][kk];
#pragma unroll
            for (int ct = 0; ct < 6; ct++) {
                bf16x8 b = *(const bf16x8*)&Bs[ct * 16 + lm][kk];
                acc[ct] = mfma16(a, b, acc[ct]);
            }
        }
        __syncthreads();
    }
    // epilogue -> LDS transpose tile Ts[96 cols][64 rows]
#pragma unroll
    for (int ct = 0; ct < 6; ct++) {
        int col = ct * 16 + lm;
        float bias = bf2f(biasp[col]);
        bool sig = (col < 64);
#pragma unroll
        for (int p = 0; p < 4; p++) {
            int lr = wv * 16 + lq * 4 + p;       // local row
            float v = acc[ct][p] + bias;
            if (sig) v = 1.f / (1.f + __expf(-v));
            Ts[col][lr] = f2bf(v);
        }
    }
    __syncthreads();
    // coalesced channel-major write: 128B runs per column
#pragma unroll
    for (int c = 0; c < 3; c++) {
        int chunk = t + c * 256;                 // 768 chunks of 8
        int col = chunk >> 3, off = (chunk & 7) * 8;
        *(uint4*)&gtc[(size_t)col * BS_TOT + row0 + off] = *(uint4*)&Ts[col][off];
    }
}

// ---------------------------------------------------------------------------
// K2 zej_scan: channel-major scan. Block = (b,m), 256 threads x 16 t's each.
// ---------------------------------------------------------------------------
__global__ __launch_bounds__(256) void zej_scan(
    const u16* __restrict__ gtc, u16* __restrict__ rmc)
{
    __shared__ float sA[4], sB[4];
    const int c = blockIdx.x;       // 0..255
    const int b = c >> 5;
    const int m = c & 31;
    const int t = threadIdx.x;
    const int lane = t & 63;
    const int wv = t >> 6;
    const size_t base = (size_t)b * SS;
    const u16* gr  = gtc + (size_t)( 0 + m) * BS_TOT + base;
    const u16* gw  = gtc + (size_t)(32 + m) * BS_TOT + base;
    const u16* gnm = gtc + (size_t)(64 + m) * BS_TOT + base;
    const int i0 = t * 16;

    uint4 w0 = *(const uint4*)(gw + i0);
    uint4 w1 = *(const uint4*)(gw + i0 + 8);
    uint4 n0 = *(const uint4*)(gnm + i0);
    uint4 n1 = *(const uint4*)(gnm + i0 + 8);

    float A = 1.f, Bc = 0.f;
#pragma unroll
    for (int j = 0; j < 16; j++) {
        float w  = bf2f(elem16(w0, w1, j));
        float nm = bf2f(elem16(n0, n1, j));
        float a = 1.f - w;
        Bc = a * Bc + w * nm;
        A *= a;
    }
    float Ai = A, Bi = Bc;
    for (int off = 1; off < 64; off <<= 1) {
        float Ap = __shfl_up(Ai, off);
        float Bp = __shfl_up(Bi, off);
        if (lane >= off) { Bi = Ai * Bp + Bi; Ai = Ai * Ap; }
    }
    if (lane == 63) { sA[wv] = Ai; sB[wv] = Bi; }
    __syncthreads();
    float Bw = 0.f;
    for (int k = 0; k < wv; k++) {
        float a2 = sA[k];
        Bw = a2 * Bw + sB[k];
    }
    float Ae = __shfl_up(Ai, 1);
    float Be = __shfl_up(Bi, 1);
    if (lane == 0) { Ae = 1.f; Be = 0.f; }
    float mem = Ae * Bw + Be;

    uint4 r0 = *(const uint4*)(gr + i0);
    uint4 r1 = *(const uint4*)(gr + i0 + 8);
    u16 o[16];
#pragma unroll
    for (int j = 0; j < 16; j++) {
        float r  = bf2f(elem16(r0, r1, j));
        float w  = bf2f(elem16(w0, w1, j));
        float nm = bf2f(elem16(n0, n1, j));
        o[j] = f2bf(r * mem);
        mem = (1.f - w) * mem + w * nm;
    }
    u16* dst = rmc + (size_t)m * BS_TOT + base + i0;
    *(uint4*)dst       = *(uint4*)&o[0];
    *(uint4*)(dst + 8) = *(uint4*)&o[8];
}

// ---------------------------------------------------------------------------
// K4 zej_out: out = tanh(xb @ Wo_x (K=1024) + rm @ Wpm (K=32) + bpm). f32 out.
// SWAPPED-OPERAND MFMA (mfma(b,a,acc)): accumulator reg-dim = n -> float4
// stores + float4 bias loads (epilogue 16 dwordx4 vs 64 dword).
// K=32 tail transposes its own rmc slab in LDS (kills the rmt kernel).
// ---------------------------------------------------------------------------
__global__ __launch_bounds__(256) void zej_out(
    const u16* __restrict__ xb, const u16* __restrict__ rmc,
    const u16* __restrict__ WoxT, const u16* __restrict__ WpmT,
    const float* __restrict__ bpm, float* __restrict__ out)
{
    __shared__ __align__(16) u16 As[128 * 64];   // 16 KB, linear, swizzled content
    __shared__ __align__(16) u16 Bs[128 * 64];
    const int t = threadIdx.x;
    const int lane = t & 63;
    const int wv = t >> 6;
    const int wr = (wv >> 1) * 64;
    const int wc = (wv & 1) * 64;
    const int bid = blockIdx.x;                  // 0..2047
    const int lin = (bid & 7) * 256 + (bid >> 3);
    const int row0 = (lin >> 3) * 128;
    const int n0 = (lin & 7) * 128;
    const int lm = lane & 15, lq = lane >> 4;

    f32x4 acc[4][4];
    f32x4 z = {0.f, 0.f, 0.f, 0.f};
#pragma unroll
    for (int i = 0; i < 4; i++)
#pragma unroll
        for (int j = 0; j < 4; j++) acc[i][j] = z;

    // staging geometry: one gload16 = 64 lanes * 16B = 8 rows of 128B.
    const int sr = lane >> 3;              // row within 8-row stripe
    const int slot = lane & 7;             // 16B slot within row
    const int kcs = 8 * (slot ^ sr);       // pre-swizzled source column (elems)

    for (int k0 = 0; k0 < 1024; k0 += 64) {
#pragma unroll
        for (int i = 0; i < 4; i++) {
            int ra = (wv * 4 + i) * 8 + sr;
            gload16(&As[(wv * 4 + i) * 512], xb   + (size_t)(row0 + ra) * 1024 + k0 + kcs);
            gload16(&Bs[(wv * 4 + i) * 512], WoxT + (size_t)(n0  + ra) * 1024 + k0 + kcs);
        }
        __syncthreads();                   // compiler drains vmcnt(0) here
#pragma unroll
        for (int ks = 0; ks < 2; ks++) {
            bf16x8 a[4], b[4];
#pragma unroll
            for (int rt = 0; rt < 4; rt++) {
                int R = wr + rt * 16 + lm;
                int cb = (ks * 64 + lq * 16) ^ ((R & 7) << 4);
                a[rt] = *(const bf16x8*)((const char*)As + R * 128 + cb);
            }
#pragma unroll
            for (int ct = 0; ct < 4; ct++) {
                int R = wc + ct * 16 + lm;
                int cb = (ks * 64 + lq * 16) ^ ((R & 7) << 4);
                b[ct] = *(const bf16x8*)((const char*)Bs + R * 128 + cb);
            }
#pragma unroll
            for (int rt = 0; rt < 4; rt++)
#pragma unroll
                for (int ct = 0; ct < 4; ct++)
                    acc[rt][ct] = mfma16(b[ct], a[rt], acc[rt][ct]);   // swapped
        }
        __syncthreads();
    }

    // K=32 tail: rm @ WpmT. A-side from rmc slab via LDS transpose.
    {
        u16* Rs = (u16*)As;                // [32][136], reuses As region
#pragma unroll
        for (int c = 0; c < 2; c++) {
            int chunk = t + c * 256;       // 512 chunks of 8
            int m = chunk >> 4, kq = (chunk & 15) * 8;
            *(uint4*)&Rs[m * 136 + kq] = *(const uint4*)&rmc[(size_t)m * BS_TOT + row0 + kq];
        }
        const int sr2 = lane >> 2;         // 0..15
        const int slot2 = lane & 3;
        const int kcs2 = 8 * (slot2 ^ (sr2 & 3));
#pragma unroll
        for (int i = 0; i < 2; i++) {
            int ra = (wv * 2 + i) * 16 + sr2;
            gload16(&Bs[(wv * 2 + i) * 512], WpmT + (size_t)(n0 + ra) * 32 + kcs2);
        }
        __syncthreads();
        bf16x8 a[4], b[4];
#pragma unroll
        for (int rt = 0; rt < 4; rt++) {
            int R = wr + rt * 16 + lm;
#pragma unroll
            for (int j = 0; j < 8; j++)
                ((u16*)&a[rt])[j] = Rs[(lq * 8 + j) * 136 + R];
        }
#pragma unroll
        for (int ct = 0; ct < 4; ct++) {
            int R = wc + ct * 16 + lm;
            b[ct] = *(const bf16x8*)((const char*)Bs + R * 64 + ((lq * 16) ^ ((R & 3) << 4)));
        }
#pragma unroll
        for (int rt = 0; rt < 4; rt++)
#pragma unroll
            for (int ct = 0; ct < 4; ct++)
                acc[rt][ct] = mfma16(b[ct], a[rt], acc[rt][ct]);       // swapped
    }

    // swapped layout: lane&15 = R, reg-dim = n -> float4 stores
#pragma unroll
    for (int rt = 0; rt < 4; rt++) {
#pragma unroll
        for (int ct = 0; ct < 4; ct++) {
            int R = row0 + wr + rt * 16 + lm;
            int nb4 = n0 + wc + ct * 16 + lq * 4;
            float4 bias = *(const float4*)&bpm[nb4];
            float4 o;
            {
                float v = acc[rt][ct][0] + bias.x;
                float e = __expf(2.f * v); o.x = 1.f - 2.f / (e + 1.f);
            }
            {
                float v = acc[rt][ct][1] + bias.y;
                float e = __expf(2.f * v); o.y = 1.f - 2.f / (e + 1.f);
            }
            {
                float v = acc[rt][ct][2] + bias.z;
                float e = __expf(2.f * v); o.z = 1.f - 2.f / (e + 1.f);
            }
            {
                float v = acc[rt][ct][3] + bias.w;
                float e = __expf(2.f * v); o.w = 1.f - 2.f / (e + 1.f);
            }
            *(float4*)&out[(size_t)R * 1024 + nb4] = o;
        }
    }
}

// ---------------------------------------------------------------------------
extern "C" void kernel_launch(void* const* d_in, const int* in_sizes, int n_in,
                              void* d_out, int out_size, void* d_ws, size_t ws_size,
                              hipStream_t stream)
{
    const void* x  = d_in[0];
    const void* Wr = d_in[1];
    const void* br = d_in[2];
    const void* Ww = d_in[3];
    const void* bw = d_in[4];
    const void* Wm = d_in[5];
    const void* bm = d_in[6];
    const void* Wp = d_in[7];
    const void* bp = d_in[8];
    const void* Wo = d_in[9];
    const void* bo = d_in[10];
    float* out = (float*)d_out;

    char* ws = (char*)d_ws;
    u16* W3T    = (u16*)(ws + 0);              //  96*1024*2   = 196608   -> 196608
    u16* WoxT   = (u16*)(ws + 196608);         //  1024*1024*2 = 2097152  -> 2293760
    u16* WpmT   = (u16*)(ws + 2293760);        //  1024*32*2   = 65536    -> 2359296
    u16* biasp  = (u16*)(ws + 2359296);        //  96*2 -> pad 1024       -> 2360320
    float* bpm  = (float*)(ws + 2360320);      //  1024*4      = 4096     -> 2364416
    u16* gtc    = (u16*)(ws + 2364416);        //  96*32768*2  = 6291456  -> 8655872
    u16* rmc    = (u16*)(ws + 8655872);        //  32*32768*2  = 2097152  -> 10753024
    u16* xb     = (u16*)(ws + 10753024);       //  32768*1024*2= 67108864 -> 77861888
    // Wpm partials alias rmc (dead until zej_scan; wpm_b reads them in the
    // zej_gates launch, which does not touch rmc):
    float* Wpm_part = (float*)(ws + 8655872);  //  8*33*1024*4 = 1081344 (< 2097152)

    zej_prep<<<769, 256, 0, stream>>>(x, Wr, Ww, Wm, Wp, Wo, br, bw, bm, bp,
                                      W3T, WoxT, biasp, Wpm_part);
    zej_gates<<<644, 256, 0, stream>>>(x, W3T, biasp, Wpm_part, bo,
                                       gtc, xb, WpmT, bpm);
    zej_scan<<<256, 256, 0, stream>>>(gtc, rmc);
    zej_out<<<2048, 256, 0, stream>>>(xb, rmc, WoxT, WpmT, bpm, out);
}